// Round 10
// baseline (222.688 us; speedup 1.0000x reference)
//
#include <hip/hip_runtime.h>

typedef __bf16 bf16x8 __attribute__((ext_vector_type(8)));
typedef float f32x4 __attribute__((ext_vector_type(4)));
typedef unsigned short u16x4 __attribute__((ext_vector_type(4)));
typedef unsigned short u16x8 __attribute__((ext_vector_type(8)));
typedef unsigned int u32x4 __attribute__((ext_vector_type(4)));

__device__ __forceinline__ float bf2f(unsigned short h) {
    union { unsigned int u; float f; } v;
    v.u = ((unsigned int)h) << 16;
    return v.f;
}
__device__ __forceinline__ unsigned short f2bf(float f) {
    return __builtin_bit_cast(unsigned short, (__bf16)f);  // native v_cvt, RNE
}
// async global->LDS, 16B per lane; LDS dest = wave-uniform base + lane*16
__device__ __forceinline__ void glds16(const unsigned short* g, unsigned short* l) {
    __builtin_amdgcn_global_load_lds((__attribute__((address_space(1))) void*)g,
                                     (__attribute__((address_space(3))) void*)l,
                                     16, 0, 0);
}

#define MFMA16(a, b, c) __builtin_amdgcn_mfma_f32_16x16x32_bf16((a), (b), (c), 0, 0, 0)

// ---------------------------------------------------------------------------
// prep1: X f32->bf16 cvt (blocks 0..4095, float4 wide) + merged Wq|Wk|Wv
// f32->bf16 transpose into wqkvT[3072][2048] (blocks 4096..5631).
// ---------------------------------------------------------------------------
__global__ __launch_bounds__(256) void prep1(const float* __restrict__ X,
                                             const float* __restrict__ Wq,
                                             const float* __restrict__ Wk,
                                             const float* __restrict__ Wv,
                                             unsigned short* __restrict__ Xbf,
                                             unsigned short* __restrict__ wqkvT) {
    const int b = blockIdx.x;
    const int tid = threadIdx.x;
    if (b < 4096) {
        const int i = (b * 256 + tid) * 4;
        const float4 v = *(const float4*)(X + i);
        u16x4 o;
        o[0] = f2bf(v.x); o[1] = f2bf(v.y); o[2] = f2bf(v.z); o[3] = f2bf(v.w);
        *(u16x4*)(Xbf + i) = o;
        return;
    }
    __shared__ __align__(16) unsigned short Lt[64][72];  // 9216B, 16B-aligned rows
    const int b2 = b - 4096;                 // 0..1535
    const int kb = (b2 & 31) * 64;           // k-dim base (rows of W), 32 tiles
    const int nb = (b2 >> 5) * 64;           // fused out-col base 0..3071, 48 tiles
    const float* src; int scol, sld;
    if (nb < 2048)      { src = Wq; scol = nb;        sld = 2048; }
    else if (nb < 2560) { src = Wk; scol = nb - 2048; sld = 512;  }
    else                { src = Wv; scol = nb - 2560; sld = 512;  }
    const int r16 = tid >> 4, c4 = tid & 15;
#pragma unroll
    for (int i = 0; i < 4; i++) {
        const int row = r16 + 16 * i;
        const float4 v = *(const float4*)(src + (size_t)(kb + row) * sld + scol + c4 * 4);
        u16x4 o;
        o[0] = f2bf(v.x); o[1] = f2bf(v.y); o[2] = f2bf(v.z); o[3] = f2bf(v.w);
        *(u16x4*)&Lt[row][c4 * 4] = o;
    }
    __syncthreads();
#pragma unroll
    for (int i = 0; i < 4; i++) {
        const int orow = r16 + 16 * i;       // n-dim within tile
        u16x4 o;
#pragma unroll
        for (int j = 0; j < 4; j++) o[j] = Lt[c4 * 4 + j][orow];
        *(u16x4*)&wqkvT[(size_t)(nb + orow) * 2048 + kb + c4 * 4] = o;
    }
}

// ---------------------------------------------------------------------------
// gemm128_qkv: QKV = Xbf @ wqkvT^T, 128x128 tile BK=128 (r9, frozen).
// 4 waves 2x2, glds16 staging, RoPE fused, bf16 out ldc=3072; V cols
// write V^T to vt. XCD-clustered bn panels.
// ---------------------------------------------------------------------------
__global__ __launch_bounds__(256) void gemm128_qkv(const unsigned short* __restrict__ A,
                                                   const unsigned short* __restrict__ BT,
                                                   unsigned short* __restrict__ C,
                                                   unsigned short* __restrict__ vt) {
    __shared__ __align__(16) unsigned short As[128 * 128];
    __shared__ __align__(16) unsigned short Bs[128 * 128];

    const int bid = blockIdx.x;          // 0..383
    const int xcd = bid & 7;
    const int sub = bid >> 3;            // 0..47
    const int bm = (sub / 3) * 128;      // 16 m-tiles
    const int bn = (xcd * 3 + sub % 3) * 128;  // 24 n-tiles, 3 per XCD

    const int tid = threadIdx.x;
    const int lane = tid & 63;
    const int wave = tid >> 6;
    const int quad = lane >> 4;
    const int l15 = lane & 15;
    const int wm = (wave & 1) * 64;
    const int wn = (wave >> 1) * 64;

    const int srow = wave * 4 + (lane >> 4);      // 0..15 (+16 per call)
    const int sw16 = (lane & 15) ^ (srow & 7);
    const unsigned short* Ag = A + (size_t)(bm + srow) * 2048 + sw16 * 8;
    const unsigned short* Bg = BT + (size_t)(bn + srow) * 2048 + sw16 * 8;
    unsigned short* Asl = As + wave * 512;        // + i*2048 per call
    unsigned short* Bsl = Bs + wave * 512;

    f32x4 acc[4][4] = {};

    for (int k0 = 0; k0 < 2048; k0 += 128) {
#pragma unroll
        for (int i = 0; i < 8; i++) {
            glds16(Ag + (size_t)(16 * i) * 2048 + k0, Asl + i * 2048);
            glds16(Bg + (size_t)(16 * i) * 2048 + k0, Bsl + i * 2048);
        }
        __syncthreads();
#pragma unroll
        for (int ks = 0; ks < 4; ks++) {
            bf16x8 af[4], bfr[4];
#pragma unroll
            for (int mt = 0; mt < 4; mt++) {
                const int row = wm + 16 * mt + l15;
                af[mt] = __builtin_bit_cast(bf16x8,
                    *(const u32x4*)&As[row * 128 + (((quad + 4 * ks) ^ (row & 7)) * 8)]);
            }
#pragma unroll
            for (int nt = 0; nt < 4; nt++) {
                const int row = wn + 16 * nt + l15;
                bfr[nt] = __builtin_bit_cast(bf16x8,
                    *(const u32x4*)&Bs[row * 128 + (((quad + 4 * ks) ^ (row & 7)) * 8)]);
            }
#pragma unroll
            for (int mt = 0; mt < 4; mt++)
#pragma unroll
                for (int nt = 0; nt < 4; nt++)
                    acc[mt][nt] = MFMA16(af[mt], bfr[nt], acc[mt][nt]);
        }
        __syncthreads();
    }

    if (bn >= 2560) {
        // V columns: write V^T directly (no RoPE). vt[d][s], d=col-2560.
#pragma unroll
        for (int mt = 0; mt < 4; mt++)
#pragma unroll
            for (int nt = 0; nt < 4; nt++) {
                const int d = bn + wn + 16 * nt + l15 - 2560;
                const int row0 = bm + wm + 16 * mt + quad * 4;
                u16x4 o;
#pragma unroll
                for (int r = 0; r < 4; r++) o[r] = f2bf(acc[mt][nt][r]);
                *(u16x4*)&vt[(size_t)d * 2048 + row0] = o;
            }
        return;
    }

    // Q|K columns: fused RoPE (pairwise via shfl), bf16 store into qkv
#pragma unroll
    for (int mt = 0; mt < 4; mt++) {
#pragma unroll
        for (int nt = 0; nt < 4; nt++) {
            const int col = bn + wn + 16 * nt + l15;
            const int i = (col & 63) >> 1;
            const float inv = exp2f(-0.41524101186092036f * (float)i);
            const float sign = (col & 1) ? 1.0f : -1.0f;
#pragma unroll
            for (int r = 0; r < 4; r++) {
                const int row = bm + wm + 16 * mt + quad * 4 + r;
                float sn, cs;
                __sincosf((float)row * inv, &sn, &cs);
                const float partner = __shfl_xor(acc[mt][nt][r], 1, 64);
                acc[mt][nt][r] = acc[mt][nt][r] * cs + sign * partner * sn;
            }
#pragma unroll
            for (int r = 0; r < 4; r++) {
                const int row = bm + wm + 16 * mt + quad * 4 + r;
                C[(size_t)row * 3072 + col] = f2bf(acc[mt][nt][r]);
            }
        }
    }
}

// ---------------------------------------------------------------------------
// gemm_out (FALLBACK when ws too small for split-K partials): BM=64 BN=64
// BK=128 -> 1024 blocks = 4/CU (round-8 config).
// ---------------------------------------------------------------------------
__global__ __launch_bounds__(256) void gemm_out(const unsigned short* __restrict__ A,
                                                const unsigned short* __restrict__ BT,
                                                float* __restrict__ C) {
    __shared__ __align__(16) unsigned short As[64 * 128];
    __shared__ __align__(16) unsigned short Bs[64 * 128];

    const int bid = blockIdx.x;          // 0..1023
    const int xcd = bid & 7;
    const int sub = bid >> 3;            // 0..127
    const int bm = (sub >> 2) * 64;      // 32 m-tiles
    const int bn = (xcd * 4 + (sub & 3)) * 64;   // 32 n-tiles, 4 per XCD

    const int tid = threadIdx.x;
    const int lane = tid & 63;
    const int wave = tid >> 6;
    const int quad = lane >> 4;
    const int l15 = lane & 15;
    const int wm = (wave & 1) * 32;
    const int wn = (wave >> 1) * 32;

    const int srow = wave * 4 + (lane >> 4);          // 0..15
    const int sw = (lane & 15) ^ (srow & 7);          // swizzled chunk 0..15
    const unsigned short* Ag = A + (size_t)(bm + srow) * 2048 + sw * 8;
    const unsigned short* Bg = BT + (size_t)(bn + srow) * 2048 + sw * 8;
    unsigned short* Asl = As + wave * 512;            // + i*2048 per call
    unsigned short* Bsl = Bs + wave * 512;

    f32x4 acc[2][2] = {};

    for (int k0 = 0; k0 < 2048; k0 += 128) {
#pragma unroll
        for (int i = 0; i < 4; i++) {
            glds16(Ag + (size_t)(16 * i) * 2048 + k0, Asl + i * 2048);
            glds16(Bg + (size_t)(16 * i) * 2048 + k0, Bsl + i * 2048);
        }
        __syncthreads();
#pragma unroll
        for (int ks = 0; ks < 4; ks++) {
            bf16x8 af[2], bfr[2];
#pragma unroll
            for (int mt = 0; mt < 2; mt++) {
                const int row = wm + 16 * mt + l15;
                af[mt] = __builtin_bit_cast(bf16x8,
                    *(const u32x4*)&As[row * 128 + (((quad + 4 * ks) ^ (row & 7)) * 8)]);
            }
#pragma unroll
            for (int nt = 0; nt < 2; nt++) {
                const int row = wn + 16 * nt + l15;
                bfr[nt] = __builtin_bit_cast(bf16x8,
                    *(const u32x4*)&Bs[row * 128 + (((quad + 4 * ks) ^ (row & 7)) * 8)]);
            }
#pragma unroll
            for (int mt = 0; mt < 2; mt++)
#pragma unroll
                for (int nt = 0; nt < 2; nt++)
                    acc[mt][nt] = MFMA16(af[mt], bfr[nt], acc[mt][nt]);
        }
        __syncthreads();
    }

#pragma unroll
    for (int mt = 0; mt < 2; mt++) {
#pragma unroll
        for (int nt = 0; nt < 2; nt++) {
#pragma unroll
            for (int r = 0; r < 4; r++) {
                const int row = bm + wm + 16 * mt + quad * 4 + r;
                const int col = bn + wn + 16 * nt + l15;
                C[(size_t)row * 2048 + col] = acc[mt][nt][r];
            }
        }
    }
}

// ---------------------------------------------------------------------------
// gemm_out_sk: out-proj SPLIT-K2 with the highest-density tile (128x128,
// BK=64, 64 MFMA/wave/phase). 512 blocks: 256 output tiles x 2 K-halves
// (K=1024 each). MFMA-resident product = 2x the 64x64 config -- the only
// lever that breaks the block-count x density wash law measured in r3/r9.
// Writes f32 partials to ws; reduce_out sums them into d_out.
// ---------------------------------------------------------------------------
__global__ __launch_bounds__(256) void gemm_out_sk(const unsigned short* __restrict__ A,
                                                   const unsigned short* __restrict__ BT,
                                                   float* __restrict__ part) {
    __shared__ __align__(16) unsigned short As[128 * 64];
    __shared__ __align__(16) unsigned short Bs[128 * 64];

    const int bid = blockIdx.x;          // 0..511
    const int xcd = bid & 7;
    const int sub = bid >> 3;            // 0..63
    const int kh = sub & 1;              // K half
    const int t = sub >> 1;              // 0..31
    const int bm = (t >> 1) * 128;       // 16 m-tiles
    const int bn = (xcd * 2 + (t & 1)) * 128;   // 16 n-tiles, 2 per XCD
    const int kbase = kh * 1024;

    const int tid = threadIdx.x;
    const int lane = tid & 63;
    const int wave = tid >> 6;
    const int quad = lane >> 4;
    const int l15 = lane & 15;
    const int wm = (wave & 1) * 64;
    const int wn = (wave >> 1) * 64;

    // staging: rows of 64 u16 (128B), 8 lanes/row, 8 chunk slots,
    // slot (lane&7) holds global chunk (lane&7)^(row&7) (involution)
    const int srow = wave * 8 + (lane >> 3);      // 0..31 (+32 per call)
    const int sw8 = (lane & 7) ^ (srow & 7);
    const unsigned short* Ag = A + (size_t)(bm + srow) * 2048 + kbase + sw8 * 8;
    const unsigned short* Bg = BT + (size_t)(bn + srow) * 2048 + kbase + sw8 * 8;
    unsigned short* Asl = As + wave * 512;        // + i*2048 per call
    unsigned short* Bsl = Bs + wave * 512;

    f32x4 acc[4][4] = {};

    for (int k0 = 0; k0 < 1024; k0 += 64) {
#pragma unroll
        for (int i = 0; i < 4; i++) {
            glds16(Ag + (size_t)(32 * i) * 2048 + k0, Asl + i * 2048);
            glds16(Bg + (size_t)(32 * i) * 2048 + k0, Bsl + i * 2048);
        }
        __syncthreads();
#pragma unroll
        for (int ks = 0; ks < 2; ks++) {
            bf16x8 af[4], bfr[4];
#pragma unroll
            for (int mt = 0; mt < 4; mt++) {
                const int row = wm + 16 * mt + l15;
                af[mt] = __builtin_bit_cast(bf16x8,
                    *(const u32x4*)&As[row * 64 + (((quad + 4 * ks) ^ (row & 7)) * 8)]);
            }
#pragma unroll
            for (int nt = 0; nt < 4; nt++) {
                const int row = wn + 16 * nt + l15;
                bfr[nt] = __builtin_bit_cast(bf16x8,
                    *(const u32x4*)&Bs[row * 64 + (((quad + 4 * ks) ^ (row & 7)) * 8)]);
            }
#pragma unroll
            for (int mt = 0; mt < 4; mt++)
#pragma unroll
                for (int nt = 0; nt < 4; nt++)
                    acc[mt][nt] = MFMA16(af[mt], bfr[nt], acc[mt][nt]);
        }
        __syncthreads();
    }

    // partial write: part[kh][row][col] f32, coalesced (16 lanes = 16 cols)
    float* p = part + (size_t)kh * 4194304;
#pragma unroll
    for (int mt = 0; mt < 4; mt++)
#pragma unroll
        for (int nt = 0; nt < 4; nt++)
#pragma unroll
            for (int r = 0; r < 4; r++) {
                const int row = bm + wm + 16 * mt + quad * 4 + r;
                const int col = bn + wn + 16 * nt + l15;
                p[(size_t)row * 2048 + col] = acc[mt][nt][r];
            }
}

// ---------------------------------------------------------------------------
// reduce_out: d_out = part0 + part1 (f32, 2048x2048), f32x4 per thread.
// ---------------------------------------------------------------------------
__global__ __launch_bounds__(256) void reduce_out(const float* __restrict__ part,
                                                  float* __restrict__ C) {
    const int i = (blockIdx.x * 256 + threadIdx.x) * 4;
    const f32x4 a = *(const f32x4*)(part + i);
    const f32x4 b = *(const f32x4*)(part + 4194304 + i);
    f32x4 o;
#pragma unroll
    for (int j = 0; j < 4; j++) o[j] = a[j] + b[j];
    *(f32x4*)(C + i) = o;
}

// ---------------------------------------------------------------------------
// attn_wo: blocks 0..511 = flash attention (FROZEN round-6 structure);
// blocks 512..1535 = Wo f32->bf16 transpose co-scheduled into attn's idle
// third block slot (confirmed ~free in round 8). LDS aliased on Ks.
// ---------------------------------------------------------------------------
__global__ __launch_bounds__(256) void attn_wo(const unsigned short* __restrict__ qkv,
                                               const unsigned short* __restrict__ vt,
                                               unsigned short* __restrict__ attn_out,
                                               const float* __restrict__ Wo,
                                               unsigned short* __restrict__ woT) {
    const int bid = blockIdx.x;
    const int tid = threadIdx.x;

    __shared__ __align__(16) unsigned short Ks[128 * 64];   // K rows x 64 d
    __shared__ __align__(16) unsigned short Vs[64 * 128];   // V^T: 64 d x 128 kv
    __shared__ __align__(16) unsigned short St[4][32][72];  // per-wave P (q x kv)

    if (bid >= 512) {
        // ---- Wo transpose tile (64x64, float4 loads), LDS aliased on Ks ----
        unsigned short (*Lt)[72] = (unsigned short (*)[72])Ks;  // 9216B < 16KB
        const int b2 = bid - 512;            // 0..1023
        const int kb = (b2 & 31) * 64;
        const int nb = (b2 >> 5) * 64;
        const int r16 = tid >> 4, c4 = tid & 15;
#pragma unroll
        for (int i = 0; i < 4; i++) {
            const int row = r16 + 16 * i;
            const float4 v = *(const float4*)(Wo + (size_t)(kb + row) * 2048 + nb + c4 * 4);
            u16x4 o;
            o[0] = f2bf(v.x); o[1] = f2bf(v.y); o[2] = f2bf(v.z); o[3] = f2bf(v.w);
            *(u16x4*)&Lt[row][c4 * 4] = o;
        }
        __syncthreads();
#pragma unroll
        for (int i = 0; i < 4; i++) {
            const int orow = r16 + 16 * i;
            u16x4 o;
#pragma unroll
            for (int j = 0; j < 4; j++) o[j] = Lt[c4 * 4 + j][orow];
            *(u16x4*)&woT[(size_t)(nb + orow) * 2048 + kb + c4 * 4] = o;
        }
        return;
    }

    // ---- flash attention (frozen) ----
    const int kvh = bid & 7;            // XCD-clustered kv-head
    const int sub = bid >> 3;           // 0..63
    const int h = kvh * 4 + (sub & 3);  // head within kv group
    const int qb = sub >> 2;            // 0..15
    const int lane = tid & 63;
    const int wave = tid >> 6;
    const int quad = lane >> 4;
    const int l15 = lane & 15;
    const int w0 = qb * 128 + wave * 32;
    unsigned short (*Sw)[72] = St[wave];

    // K staging map (64-u16 rows, 8 chunk slots)
    const int srow = wave * 8 + (lane >> 3);
    const int swK = (lane & 7) ^ (srow & 7);
    const unsigned short* Kg = qkv + 2048 + kvh * 64 + swK * 8;  // + (kbase+srow+32i)*3072
    unsigned short* Ksl = Ks + wave * 512;
    // V staging map (128-u16 rows, 16 chunk slots)
    const int vrow = wave * 4 + (lane >> 4);
    const int swV = (lane & 15) ^ (vrow & 7);
    const unsigned short* Vg = vt + (size_t)(kvh * 64 + vrow) * 2048 + swV * 8;  // + 16i*2048 + kbase
    unsigned short* Vsl = Vs + wave * 512;

    // Q fragments (MFMA B-operand: n=q=l15, k=quad*8+j), pre-scaled by
    // log2e/8 (shift-invariant softmax: no exponent bias needed).
    const float QSCALE = 0.18033688011111093f;  // 0.125 * log2(e)
    bf16x8 qf[2][2];
#pragma unroll
    for (int mt = 0; mt < 2; mt++)
#pragma unroll
        for (int ks = 0; ks < 2; ks++) {
            u32x4 raw = *(const u32x4*)&qkv[(size_t)(w0 + 16 * mt + l15) * 3072 + h * 64 + quad * 8 + 32 * ks];
            u16x8 t = __builtin_bit_cast(u16x8, raw);
#pragma unroll
            for (int j = 0; j < 8; j++) t[j] = f2bf(bf2f(t[j]) * QSCALE);
            qf[mt][ks] = __builtin_bit_cast(bf16x8, t);
        }

    bf16x8 ones;
#pragma unroll
    for (int j = 0; j < 8; j++) ones[j] = (__bf16)1.0f;

    f32x4 acc_o[2][4] = {};
    f32x4 acc_l[2] = {};

    for (int kb2 = 0; kb2 < 16; kb2++) {
        const int kbase = kb2 * 128;
#pragma unroll
        for (int i = 0; i < 4; i++) {
            glds16(Kg + (size_t)(kbase + srow + 32 * i) * 3072, Ksl + i * 2048);
            glds16(Vg + (size_t)(16 * i) * 2048 + kbase, Vsl + i * 2048);
        }
        __syncthreads();

#pragma unroll
        for (int kh = 0; kh < 2; kh++) {
            // S^T = K Q^T : A = K-frag (m=kv), B = Q-frag (n=q)
            f32x4 st[2][4] = {};
            __builtin_amdgcn_s_setprio(1);
#pragma unroll
            for (int n = 0; n < 4; n++) {
                const int row = kh * 64 + 16 * n + l15;
                const bf16x8 kf0 = __builtin_bit_cast(bf16x8,
                    *(const u32x4*)&Ks[row * 64 + ((quad ^ (l15 & 7)) * 8)]);
                const bf16x8 kf1 = __builtin_bit_cast(bf16x8,
                    *(const u32x4*)&Ks[row * 64 + (((quad + 4) ^ (l15 & 7)) * 8)]);
#pragma unroll
                for (int mt = 0; mt < 2; mt++) {
                    st[mt][n] = MFMA16(kf0, qf[mt][0], st[mt][n]);
                    st[mt][n] = MFMA16(kf1, qf[mt][1], st[mt][n]);
                }
            }
            __builtin_amdgcn_s_setprio(0);

            // p = exp2(st); lane holds q=l15, kv=16n+quad*4+r
#pragma unroll
            for (int mt = 0; mt < 2; mt++)
#pragma unroll
                for (int n = 0; n < 4; n++) {
                    u16x4 pk;
#pragma unroll
                    for (int r = 0; r < 4; r++)
                        pk[r] = f2bf(exp2f(st[mt][n][r]));
                    *(u16x4*)&Sw[16 * mt + l15][16 * n + quad * 4] = pk;
                }

            // P A-frags (m=q=l15, k=kv=quad*8+j) straight from Sw rows
            bf16x8 pf[2][2];
#pragma unroll
            for (int mt = 0; mt < 2; mt++) {
                pf[mt][0] = __builtin_bit_cast(bf16x8, *(const u32x4*)&Sw[16 * mt + l15][quad * 8]);
                pf[mt][1] = __builtin_bit_cast(bf16x8, *(const u32x4*)&Sw[16 * mt + l15][quad * 8 + 32]);
            }

            __builtin_amdgcn_s_setprio(1);
            // row sums: acc_l[mt] += P @ ones  (C-rows match acc_o's rows)
#pragma unroll
            for (int mt = 0; mt < 2; mt++) {
                acc_l[mt] = MFMA16(pf[mt][0], ones, acc_l[mt]);
                acc_l[mt] = MFMA16(pf[mt][1], ones, acc_l[mt]);
            }

            // O += P @ V : B = V^T rows (n=d=l15, k=kv)
#pragma unroll
            for (int nt = 0; nt < 4; nt++) {
                const int row = 16 * nt + l15;
                const int c0 = kh * 8 + (quad ^ (l15 & 7));
                const int c1 = kh * 8 + ((quad + 4) ^ (l15 & 7));
                const bf16x8 vf0 = __builtin_bit_cast(bf16x8, *(const u32x4*)&Vs[row * 128 + c0 * 8]);
                const bf16x8 vf1 = __builtin_bit_cast(bf16x8, *(const u32x4*)&Vs[row * 128 + c1 * 8]);
#pragma unroll
                for (int mt = 0; mt < 2; mt++) {
                    acc_o[mt][nt] = MFMA16(pf[mt][0], vf0, acc_o[mt][nt]);
                    acc_o[mt][nt] = MFMA16(pf[mt][1], vf1, acc_o[mt][nt]);
                }
            }
            __builtin_amdgcn_s_setprio(0);
        }
        __syncthreads();
    }

    // epilogue: acc_o and acc_l share lane layout q=quad*4+r (+16mt), d=16nt+l15
#pragma unroll
    for (int mt = 0; mt < 2; mt++) {
        float linv[4];
#pragma unroll
        for (int r = 0; r < 4; r++) linv[r] = 1.0f / acc_l[mt][r];
#pragma unroll
        for (int nt = 0; nt < 4; nt++)
#pragma unroll
            for (int r = 0; r < 4; r++)
                attn_out[(size_t)(w0 + 16 * mt + quad * 4 + r) * 2048 + h * 64 + 16 * nt + l15] =
                    f2bf(acc_o[mt][nt][r] * linv[r]);
    }
}

// ---------------------------------------------------------------------------
extern "C" void kernel_launch(void* const* d_in, const int* in_sizes, int n_in,
                              void* d_out, int out_size, void* d_ws, size_t ws_size,
                              hipStream_t stream) {
    (void)in_sizes; (void)n_in; (void)out_size;

    const float* X  = (const float*)d_in[0];
    const float* Wq = (const float*)d_in[1];
    const float* Wk = (const float*)d_in[2];
    const float* Wv = (const float*)d_in[3];
    const float* Wo = (const float*)d_in[4];

    // ws (u16): phase1 Xbf[0..4.19M) wqkvT[4.19M..10.49M)
    //           phase2 attnO[1.05M..5.24M) woT[5.24M..9.44M)
    //           phase3 split-K partials (f32) at u16-offset 9.44M,
    //                  2 x 2048x2048 f32 = 33.6MB -> ws end 52.4MB (guarded)
    // d_out (u16): qkv Q|K cols [0..6.29M); vt in free tail [6.29M..7.34M)
    unsigned short* ws16  = (unsigned short*)d_ws;
    unsigned short* Xbf   = ws16;
    unsigned short* wqkvT = ws16 + (size_t)4194304;
    unsigned short* qkv   = (unsigned short*)d_out;
    unsigned short* vt    = (unsigned short*)d_out + (size_t)6291456;
    unsigned short* attnO = ws16 + (size_t)1048576;
    unsigned short* woT   = ws16 + (size_t)5242880;
    float*          part  = (float*)(ws16 + (size_t)9437184);

    // X cvt (4096 blocks) + Wqkv 64x64 float4 transpose (1536 blocks)
    prep1<<<5632, 256, 0, stream>>>(X, Wq, Wk, Wv, Xbf, wqkvT);

    // QKV = X @ [Wq|Wk|Wv] -> Q|K (RoPE'd) into qkv, V^T into vt (BK=128)
    gemm128_qkv<<<384, 256, 0, stream>>>(Xbf, wqkvT, qkv, vt);

    // attention (blocks 0..511) + Wo transpose (blocks 512..1535)
    attn_wo<<<1536, 256, 0, stream>>>(qkv, vt, attnO, Wo, woT);

    // out = attnO @ Wo -> f32 into d_out
    if (ws_size >= (size_t)52428800) {
        // split-K2, 128^2/BK=64 tile (2x MFMA-resident product) + reduce
        gemm_out_sk<<<512, 256, 0, stream>>>(attnO, woT, part);
        reduce_out<<<4096, 256, 0, stream>>>(part, (float*)d_out);
    } else {
        gemm_out<<<1024, 256, 0, stream>>>(attnO, woT, (float*)d_out);
    }
}

// Round 11
// 220.255 us; speedup vs baseline: 1.0110x; 1.0110x over previous
//
#include <hip/hip_runtime.h>

typedef __bf16 bf16x8 __attribute__((ext_vector_type(8)));
typedef float f32x4 __attribute__((ext_vector_type(4)));
typedef unsigned short u16x4 __attribute__((ext_vector_type(4)));
typedef unsigned short u16x8 __attribute__((ext_vector_type(8)));
typedef unsigned int u32x4 __attribute__((ext_vector_type(4)));

__device__ __forceinline__ float bf2f(unsigned short h) {
    union { unsigned int u; float f; } v;
    v.u = ((unsigned int)h) << 16;
    return v.f;
}
__device__ __forceinline__ unsigned short f2bf(float f) {
    return __builtin_bit_cast(unsigned short, (__bf16)f);  // native v_cvt, RNE
}
// async global->LDS, 16B per lane; LDS dest = wave-uniform base + lane*16
__device__ __forceinline__ void glds16(const unsigned short* g, unsigned short* l) {
    __builtin_amdgcn_global_load_lds((__attribute__((address_space(1))) void*)g,
                                     (__attribute__((address_space(3))) void*)l,
                                     16, 0, 0);
}

#define MFMA16(a, b, c) __builtin_amdgcn_mfma_f32_16x16x32_bf16((a), (b), (c), 0, 0, 0)

// ---------------------------------------------------------------------------
// prep1: X f32->bf16 cvt (blocks 0..4095, float4 wide) + merged Wq|Wk|Wv
// f32->bf16 transpose into wqkvT[3072][2048] (blocks 4096..5631).
// ---------------------------------------------------------------------------
__global__ __launch_bounds__(256) void prep1(const float* __restrict__ X,
                                             const float* __restrict__ Wq,
                                             const float* __restrict__ Wk,
                                             const float* __restrict__ Wv,
                                             unsigned short* __restrict__ Xbf,
                                             unsigned short* __restrict__ wqkvT) {
    const int b = blockIdx.x;
    const int tid = threadIdx.x;
    if (b < 4096) {
        const int i = (b * 256 + tid) * 4;
        const float4 v = *(const float4*)(X + i);
        u16x4 o;
        o[0] = f2bf(v.x); o[1] = f2bf(v.y); o[2] = f2bf(v.z); o[3] = f2bf(v.w);
        *(u16x4*)(Xbf + i) = o;
        return;
    }
    __shared__ __align__(16) unsigned short Lt[64][72];  // 9216B, 16B-aligned rows
    const int b2 = b - 4096;                 // 0..1535
    const int kb = (b2 & 31) * 64;           // k-dim base (rows of W), 32 tiles
    const int nb = (b2 >> 5) * 64;           // fused out-col base 0..3071, 48 tiles
    const float* src; int scol, sld;
    if (nb < 2048)      { src = Wq; scol = nb;        sld = 2048; }
    else if (nb < 2560) { src = Wk; scol = nb - 2048; sld = 512;  }
    else                { src = Wv; scol = nb - 2560; sld = 512;  }
    const int r16 = tid >> 4, c4 = tid & 15;
#pragma unroll
    for (int i = 0; i < 4; i++) {
        const int row = r16 + 16 * i;
        const float4 v = *(const float4*)(src + (size_t)(kb + row) * sld + scol + c4 * 4);
        u16x4 o;
        o[0] = f2bf(v.x); o[1] = f2bf(v.y); o[2] = f2bf(v.z); o[3] = f2bf(v.w);
        *(u16x4*)&Lt[row][c4 * 4] = o;
    }
    __syncthreads();
#pragma unroll
    for (int i = 0; i < 4; i++) {
        const int orow = r16 + 16 * i;       // n-dim within tile
        u16x4 o;
#pragma unroll
        for (int j = 0; j < 4; j++) o[j] = Lt[c4 * 4 + j][orow];
        *(u16x4*)&wqkvT[(size_t)(nb + orow) * 2048 + kb + c4 * 4] = o;
    }
}

// ---------------------------------------------------------------------------
// gemm128_qkv: QKV = Xbf @ wqkvT^T, 128x128 tile BK=128 (r9, frozen).
// 4 waves 2x2, glds16 staging, RoPE fused, bf16 out ldc=3072; V cols
// write V^T to vt. XCD-clustered bn panels.
// ---------------------------------------------------------------------------
__global__ __launch_bounds__(256) void gemm128_qkv(const unsigned short* __restrict__ A,
                                                   const unsigned short* __restrict__ BT,
                                                   unsigned short* __restrict__ C,
                                                   unsigned short* __restrict__ vt) {
    __shared__ __align__(16) unsigned short As[128 * 128];
    __shared__ __align__(16) unsigned short Bs[128 * 128];

    const int bid = blockIdx.x;          // 0..383
    const int xcd = bid & 7;
    const int sub = bid >> 3;            // 0..47
    const int bm = (sub / 3) * 128;      // 16 m-tiles
    const int bn = (xcd * 3 + sub % 3) * 128;  // 24 n-tiles, 3 per XCD

    const int tid = threadIdx.x;
    const int lane = tid & 63;
    const int wave = tid >> 6;
    const int quad = lane >> 4;
    const int l15 = lane & 15;
    const int wm = (wave & 1) * 64;
    const int wn = (wave >> 1) * 64;

    const int srow = wave * 4 + (lane >> 4);      // 0..15 (+16 per call)
    const int sw16 = (lane & 15) ^ (srow & 7);
    const unsigned short* Ag = A + (size_t)(bm + srow) * 2048 + sw16 * 8;
    const unsigned short* Bg = BT + (size_t)(bn + srow) * 2048 + sw16 * 8;
    unsigned short* Asl = As + wave * 512;        // + i*2048 per call
    unsigned short* Bsl = Bs + wave * 512;

    f32x4 acc[4][4] = {};

    for (int k0 = 0; k0 < 2048; k0 += 128) {
#pragma unroll
        for (int i = 0; i < 8; i++) {
            glds16(Ag + (size_t)(16 * i) * 2048 + k0, Asl + i * 2048);
            glds16(Bg + (size_t)(16 * i) * 2048 + k0, Bsl + i * 2048);
        }
        __syncthreads();
#pragma unroll
        for (int ks = 0; ks < 4; ks++) {
            bf16x8 af[4], bfr[4];
#pragma unroll
            for (int mt = 0; mt < 4; mt++) {
                const int row = wm + 16 * mt + l15;
                af[mt] = __builtin_bit_cast(bf16x8,
                    *(const u32x4*)&As[row * 128 + (((quad + 4 * ks) ^ (row & 7)) * 8)]);
            }
#pragma unroll
            for (int nt = 0; nt < 4; nt++) {
                const int row = wn + 16 * nt + l15;
                bfr[nt] = __builtin_bit_cast(bf16x8,
                    *(const u32x4*)&Bs[row * 128 + (((quad + 4 * ks) ^ (row & 7)) * 8)]);
            }
#pragma unroll
            for (int mt = 0; mt < 4; mt++)
#pragma unroll
                for (int nt = 0; nt < 4; nt++)
                    acc[mt][nt] = MFMA16(af[mt], bfr[nt], acc[mt][nt]);
        }
        __syncthreads();
    }

    if (bn >= 2560) {
        // V columns: write V^T directly (no RoPE). vt[d][s], d=col-2560.
#pragma unroll
        for (int mt = 0; mt < 4; mt++)
#pragma unroll
            for (int nt = 0; nt < 4; nt++) {
                const int d = bn + wn + 16 * nt + l15 - 2560;
                const int row0 = bm + wm + 16 * mt + quad * 4;
                u16x4 o;
#pragma unroll
                for (int r = 0; r < 4; r++) o[r] = f2bf(acc[mt][nt][r]);
                *(u16x4*)&vt[(size_t)d * 2048 + row0] = o;
            }
        return;
    }

    // Q|K columns: fused RoPE (pairwise via shfl), bf16 store into qkv
#pragma unroll
    for (int mt = 0; mt < 4; mt++) {
#pragma unroll
        for (int nt = 0; nt < 4; nt++) {
            const int col = bn + wn + 16 * nt + l15;
            const int i = (col & 63) >> 1;
            const float inv = exp2f(-0.41524101186092036f * (float)i);
            const float sign = (col & 1) ? 1.0f : -1.0f;
#pragma unroll
            for (int r = 0; r < 4; r++) {
                const int row = bm + wm + 16 * mt + quad * 4 + r;
                float sn, cs;
                __sincosf((float)row * inv, &sn, &cs);
                const float partner = __shfl_xor(acc[mt][nt][r], 1, 64);
                acc[mt][nt][r] = acc[mt][nt][r] * cs + sign * partner * sn;
            }
#pragma unroll
            for (int r = 0; r < 4; r++) {
                const int row = bm + wm + 16 * mt + quad * 4 + r;
                C[(size_t)row * 3072 + col] = f2bf(acc[mt][nt][r]);
            }
        }
    }
}

// ---------------------------------------------------------------------------
// gemm_out (out-proj): C[2048][2048] f32 = A @ BT^T, bf16 in.
// BM=64 BN=64 BK=128 -> 1024 blocks = 4 blocks/CU (round-8 config, best
// measured). Split-K2 variant measured NEGATIVE (r10: reduce tax > gain);
// tile/density permutations all null (r3/r9) -> this GEMM is at the
// m102-documented shape plateau for the m97 structure. Frozen.
// ---------------------------------------------------------------------------
__global__ __launch_bounds__(256) void gemm_out(const unsigned short* __restrict__ A,
                                                const unsigned short* __restrict__ BT,
                                                float* __restrict__ C) {
    __shared__ __align__(16) unsigned short As[64 * 128];
    __shared__ __align__(16) unsigned short Bs[64 * 128];

    const int bid = blockIdx.x;          // 0..1023
    const int xcd = bid & 7;
    const int sub = bid >> 3;            // 0..127
    const int bm = (sub >> 2) * 64;      // 32 m-tiles
    const int bn = (xcd * 4 + (sub & 3)) * 64;   // 32 n-tiles, 4 per XCD

    const int tid = threadIdx.x;
    const int lane = tid & 63;
    const int wave = tid >> 6;
    const int quad = lane >> 4;
    const int l15 = lane & 15;
    const int wm = (wave & 1) * 32;
    const int wn = (wave >> 1) * 32;

    const int srow = wave * 4 + (lane >> 4);          // 0..15
    const int sw = (lane & 15) ^ (srow & 7);          // swizzled chunk 0..15
    const unsigned short* Ag = A + (size_t)(bm + srow) * 2048 + sw * 8;
    const unsigned short* Bg = BT + (size_t)(bn + srow) * 2048 + sw * 8;
    unsigned short* Asl = As + wave * 512;            // + i*2048 per call
    unsigned short* Bsl = Bs + wave * 512;

    f32x4 acc[2][2] = {};

    for (int k0 = 0; k0 < 2048; k0 += 128) {
#pragma unroll
        for (int i = 0; i < 4; i++) {
            glds16(Ag + (size_t)(16 * i) * 2048 + k0, Asl + i * 2048);
            glds16(Bg + (size_t)(16 * i) * 2048 + k0, Bsl + i * 2048);
        }
        __syncthreads();
#pragma unroll
        for (int ks = 0; ks < 4; ks++) {
            bf16x8 af[2], bfr[2];
#pragma unroll
            for (int mt = 0; mt < 2; mt++) {
                const int row = wm + 16 * mt + l15;
                af[mt] = __builtin_bit_cast(bf16x8,
                    *(const u32x4*)&As[row * 128 + (((quad + 4 * ks) ^ (row & 7)) * 8)]);
            }
#pragma unroll
            for (int nt = 0; nt < 2; nt++) {
                const int row = wn + 16 * nt + l15;
                bfr[nt] = __builtin_bit_cast(bf16x8,
                    *(const u32x4*)&Bs[row * 128 + (((quad + 4 * ks) ^ (row & 7)) * 8)]);
            }
#pragma unroll
            for (int mt = 0; mt < 2; mt++)
#pragma unroll
                for (int nt = 0; nt < 2; nt++)
                    acc[mt][nt] = MFMA16(af[mt], bfr[nt], acc[mt][nt]);
        }
        __syncthreads();
    }

#pragma unroll
    for (int mt = 0; mt < 2; mt++) {
#pragma unroll
        for (int nt = 0; nt < 2; nt++) {
#pragma unroll
            for (int r = 0; r < 4; r++) {
                const int row = bm + wm + 16 * mt + quad * 4 + r;
                const int col = bn + wn + 16 * nt + l15;
                C[(size_t)row * 2048 + col] = acc[mt][nt][r];
            }
        }
    }
}

// ---------------------------------------------------------------------------
// attn_wo: blocks 0..511 = flash attention (FROZEN round-6 structure);
// blocks 512..1535 = Wo f32->bf16 transpose co-scheduled into attn's idle
// third block slot (confirmed ~free in round 8). LDS aliased on Ks.
// ---------------------------------------------------------------------------
__global__ __launch_bounds__(256) void attn_wo(const unsigned short* __restrict__ qkv,
                                               const unsigned short* __restrict__ vt,
                                               unsigned short* __restrict__ attn_out,
                                               const float* __restrict__ Wo,
                                               unsigned short* __restrict__ woT) {
    const int bid = blockIdx.x;
    const int tid = threadIdx.x;

    __shared__ __align__(16) unsigned short Ks[128 * 64];   // K rows x 64 d
    __shared__ __align__(16) unsigned short Vs[64 * 128];   // V^T: 64 d x 128 kv
    __shared__ __align__(16) unsigned short St[4][32][72];  // per-wave P (q x kv)

    if (bid >= 512) {
        // ---- Wo transpose tile (64x64, float4 loads), LDS aliased on Ks ----
        unsigned short (*Lt)[72] = (unsigned short (*)[72])Ks;  // 9216B < 16KB
        const int b2 = bid - 512;            // 0..1023
        const int kb = (b2 & 31) * 64;
        const int nb = (b2 >> 5) * 64;
        const int r16 = tid >> 4, c4 = tid & 15;
#pragma unroll
        for (int i = 0; i < 4; i++) {
            const int row = r16 + 16 * i;
            const float4 v = *(const float4*)(Wo + (size_t)(kb + row) * 2048 + nb + c4 * 4);
            u16x4 o;
            o[0] = f2bf(v.x); o[1] = f2bf(v.y); o[2] = f2bf(v.z); o[3] = f2bf(v.w);
            *(u16x4*)&Lt[row][c4 * 4] = o;
        }
        __syncthreads();
#pragma unroll
        for (int i = 0; i < 4; i++) {
            const int orow = r16 + 16 * i;
            u16x4 o;
#pragma unroll
            for (int j = 0; j < 4; j++) o[j] = Lt[c4 * 4 + j][orow];
            *(u16x4*)&woT[(size_t)(nb + orow) * 2048 + kb + c4 * 4] = o;
        }
        return;
    }

    // ---- flash attention (frozen) ----
    const int kvh = bid & 7;            // XCD-clustered kv-head
    const int sub = bid >> 3;           // 0..63
    const int h = kvh * 4 + (sub & 3);  // head within kv group
    const int qb = sub >> 2;            // 0..15
    const int lane = tid & 63;
    const int wave = tid >> 6;
    const int quad = lane >> 4;
    const int l15 = lane & 15;
    const int w0 = qb * 128 + wave * 32;
    unsigned short (*Sw)[72] = St[wave];

    // K staging map (64-u16 rows, 8 chunk slots)
    const int srow = wave * 8 + (lane >> 3);
    const int swK = (lane & 7) ^ (srow & 7);
    const unsigned short* Kg = qkv + 2048 + kvh * 64 + swK * 8;  // + (kbase+srow+32i)*3072
    unsigned short* Ksl = Ks + wave * 512;
    // V staging map (128-u16 rows, 16 chunk slots)
    const int vrow = wave * 4 + (lane >> 4);
    const int swV = (lane & 15) ^ (vrow & 7);
    const unsigned short* Vg = vt + (size_t)(kvh * 64 + vrow) * 2048 + swV * 8;  // + 16i*2048 + kbase
    unsigned short* Vsl = Vs + wave * 512;

    // Q fragments (MFMA B-operand: n=q=l15, k=quad*8+j), pre-scaled by
    // log2e/8 (shift-invariant softmax: no exponent bias needed).
    const float QSCALE = 0.18033688011111093f;  // 0.125 * log2(e)
    bf16x8 qf[2][2];
#pragma unroll
    for (int mt = 0; mt < 2; mt++)
#pragma unroll
        for (int ks = 0; ks < 2; ks++) {
            u32x4 raw = *(const u32x4*)&qkv[(size_t)(w0 + 16 * mt + l15) * 3072 + h * 64 + quad * 8 + 32 * ks];
            u16x8 t = __builtin_bit_cast(u16x8, raw);
#pragma unroll
            for (int j = 0; j < 8; j++) t[j] = f2bf(bf2f(t[j]) * QSCALE);
            qf[mt][ks] = __builtin_bit_cast(bf16x8, t);
        }

    bf16x8 ones;
#pragma unroll
    for (int j = 0; j < 8; j++) ones[j] = (__bf16)1.0f;

    f32x4 acc_o[2][4] = {};
    f32x4 acc_l[2] = {};

    for (int kb2 = 0; kb2 < 16; kb2++) {
        const int kbase = kb2 * 128;
#pragma unroll
        for (int i = 0; i < 4; i++) {
            glds16(Kg + (size_t)(kbase + srow + 32 * i) * 3072, Ksl + i * 2048);
            glds16(Vg + (size_t)(16 * i) * 2048 + kbase, Vsl + i * 2048);
        }
        __syncthreads();

#pragma unroll
        for (int kh = 0; kh < 2; kh++) {
            // S^T = K Q^T : A = K-frag (m=kv), B = Q-frag (n=q)
            f32x4 st[2][4] = {};
            __builtin_amdgcn_s_setprio(1);
#pragma unroll
            for (int n = 0; n < 4; n++) {
                const int row = kh * 64 + 16 * n + l15;
                const bf16x8 kf0 = __builtin_bit_cast(bf16x8,
                    *(const u32x4*)&Ks[row * 64 + ((quad ^ (l15 & 7)) * 8)]);
                const bf16x8 kf1 = __builtin_bit_cast(bf16x8,
                    *(const u32x4*)&Ks[row * 64 + (((quad + 4) ^ (l15 & 7)) * 8)]);
#pragma unroll
                for (int mt = 0; mt < 2; mt++) {
                    st[mt][n] = MFMA16(kf0, qf[mt][0], st[mt][n]);
                    st[mt][n] = MFMA16(kf1, qf[mt][1], st[mt][n]);
                }
            }
            __builtin_amdgcn_s_setprio(0);

            // p = exp2(st); lane holds q=l15, kv=16n+quad*4+r
#pragma unroll
            for (int mt = 0; mt < 2; mt++)
#pragma unroll
                for (int n = 0; n < 4; n++) {
                    u16x4 pk;
#pragma unroll
                    for (int r = 0; r < 4; r++)
                        pk[r] = f2bf(exp2f(st[mt][n][r]));
                    *(u16x4*)&Sw[16 * mt + l15][16 * n + quad * 4] = pk;
                }

            // P A-frags (m=q=l15, k=kv=quad*8+j) straight from Sw rows
            bf16x8 pf[2][2];
#pragma unroll
            for (int mt = 0; mt < 2; mt++) {
                pf[mt][0] = __builtin_bit_cast(bf16x8, *(const u32x4*)&Sw[16 * mt + l15][quad * 8]);
                pf[mt][1] = __builtin_bit_cast(bf16x8, *(const u32x4*)&Sw[16 * mt + l15][quad * 8 + 32]);
            }

            __builtin_amdgcn_s_setprio(1);
            // row sums: acc_l[mt] += P @ ones  (C-rows match acc_o's rows)
#pragma unroll
            for (int mt = 0; mt < 2; mt++) {
                acc_l[mt] = MFMA16(pf[mt][0], ones, acc_l[mt]);
                acc_l[mt] = MFMA16(pf[mt][1], ones, acc_l[mt]);
            }

            // O += P @ V : B = V^T rows (n=d=l15, k=kv)
#pragma unroll
            for (int nt = 0; nt < 4; nt++) {
                const int row = 16 * nt + l15;
                const int c0 = kh * 8 + (quad ^ (l15 & 7));
                const int c1 = kh * 8 + ((quad + 4) ^ (l15 & 7));
                const bf16x8 vf0 = __builtin_bit_cast(bf16x8, *(const u32x4*)&Vs[row * 128 + c0 * 8]);
                const bf16x8 vf1 = __builtin_bit_cast(bf16x8, *(const u32x4*)&Vs[row * 128 + c1 * 8]);
#pragma unroll
                for (int mt = 0; mt < 2; mt++) {
                    acc_o[mt][nt] = MFMA16(pf[mt][0], vf0, acc_o[mt][nt]);
                    acc_o[mt][nt] = MFMA16(pf[mt][1], vf1, acc_o[mt][nt]);
                }
            }
            __builtin_amdgcn_s_setprio(0);
        }
        __syncthreads();
    }

    // epilogue: acc_o and acc_l share lane layout q=quad*4+r (+16mt), d=16nt+l15
#pragma unroll
    for (int mt = 0; mt < 2; mt++) {
        float linv[4];
#pragma unroll
        for (int r = 0; r < 4; r++) linv[r] = 1.0f / acc_l[mt][r];
#pragma unroll
        for (int nt = 0; nt < 4; nt++)
#pragma unroll
            for (int r = 0; r < 4; r++)
                attn_out[(size_t)(w0 + 16 * mt + quad * 4 + r) * 2048 + h * 64 + 16 * nt + l15] =
                    f2bf(acc_o[mt][nt][r] * linv[r]);
    }
}

// ---------------------------------------------------------------------------
extern "C" void kernel_launch(void* const* d_in, const int* in_sizes, int n_in,
                              void* d_out, int out_size, void* d_ws, size_t ws_size,
                              hipStream_t stream) {
    (void)in_sizes; (void)n_in; (void)out_size; (void)ws_size;

    const float* X  = (const float*)d_in[0];
    const float* Wq = (const float*)d_in[1];
    const float* Wk = (const float*)d_in[2];
    const float* Wv = (const float*)d_in[3];
    const float* Wo = (const float*)d_in[4];

    // ws (u16): phase1 Xbf[0..4.19M) wqkvT[4.19M..10.49M)
    //           phase2 attnO[1.05M..5.24M) woT[5.24M..9.44M)
    // d_out (u16): qkv Q|K cols [0..6.29M); vt in free tail [6.29M..7.34M)
    unsigned short* ws16  = (unsigned short*)d_ws;
    unsigned short* Xbf   = ws16;
    unsigned short* wqkvT = ws16 + (size_t)4194304;
    unsigned short* qkv   = (unsigned short*)d_out;
    unsigned short* vt    = (unsigned short*)d_out + (size_t)6291456;
    unsigned short* attnO = ws16 + (size_t)1048576;
    unsigned short* woT   = ws16 + (size_t)5242880;

    // X cvt (4096 blocks) + Wqkv 64x64 float4 transpose (1536 blocks)
    prep1<<<5632, 256, 0, stream>>>(X, Wq, Wk, Wv, Xbf, wqkvT);

    // QKV = X @ [Wq|Wk|Wv] -> Q|K (RoPE'd) into qkv, V^T into vt (BK=128)
    gemm128_qkv<<<384, 256, 0, stream>>>(Xbf, wqkvT, qkv, vt);

    // attention (blocks 0..511) + Wo transpose (blocks 512..1535)
    attn_wo<<<1536, 256, 0, stream>>>(qkv, vt, attnO, Wo, woT);

    // out = attnO @ Wo -> f32 into d_out; 1024 blocks = 4/CU
    gemm_out<<<1024, 256, 0, stream>>>(attnO, woT, (float*)d_out);
}